// Round 1
// baseline (126.503 us; speedup 1.0000x reference)
//
#include <hip/hip_runtime.h>

// GSA loss: pred [B=2,1,64,64] fp32, token [B,4096,4096] fp32 -> scalar fp32.
// loss = 2 - s_fa/s_f - s_bb/s_b with
//   T   = sum t_ij
//   s_f = sum p_i t_ij        (row-weighted)
//   s_c = sum t_ij p_j        (col-weighted; token NOT symmetric)
//   s_fa= sum p_i t_ij p_j
//   s_b = T - s_f
//   s_bb= T - s_f - s_c + s_fa

#define HW   4096
#define HW4  1024   // HW / 4 (float4 granularity)

__global__ __launch_bounds__(256) void gsa_reduce(
    const float* __restrict__ pred,
    const float* __restrict__ token,
    double* __restrict__ acc,   // acc[0..3] = T, s_f, s_c, s_fa
    int total4)                 // B*HW*HW/4
{
    float tT = 0.f, tF = 0.f, tC = 0.f, tFA = 0.f;

    const float4* __restrict__ tok4  = (const float4*)token;
    const float4* __restrict__ pred4 = (const float4*)pred;

    int idx    = blockIdx.x * blockDim.x + threadIdx.x;
    int stride = gridDim.x * blockDim.x;

    for (int i4 = idx; i4 < total4; i4 += stride) {
        int j4  = i4 & (HW4 - 1);        // float4 column index
        int row = i4 >> 10;              // global row in [0, B*HW)
        int b   = row >> 12;             // row / HW

        float  pi = pred[row];                 // p[b,i], L1/L2 hot (32 KB)
        float4 pj = pred4[b * HW4 + j4];       // p[b, 4j..4j+3]
        float4 t  = tok4[i4];

        float s = t.x + t.y + t.z + t.w;
        float d = t.x * pj.x + t.y * pj.y + t.z * pj.z + t.w * pj.w;

        tT  += s;
        tF  += pi * s;
        tC  += d;
        tFA += pi * d;
    }

    // wave (64-lane) butterfly reduce
    for (int off = 32; off > 0; off >>= 1) {
        tT  += __shfl_down(tT,  off);
        tF  += __shfl_down(tF,  off);
        tC  += __shfl_down(tC,  off);
        tFA += __shfl_down(tFA, off);
    }

    __shared__ double sm[4][4];   // [wave][accum], 256 threads = 4 waves
    int wave = threadIdx.x >> 6;
    int lane = threadIdx.x & 63;
    if (lane == 0) {
        sm[wave][0] = (double)tT;
        sm[wave][1] = (double)tF;
        sm[wave][2] = (double)tC;
        sm[wave][3] = (double)tFA;
    }
    __syncthreads();

    if (threadIdx.x == 0) {
        double aT  = sm[0][0] + sm[1][0] + sm[2][0] + sm[3][0];
        double aF  = sm[0][1] + sm[1][1] + sm[2][1] + sm[3][1];
        double aC  = sm[0][2] + sm[1][2] + sm[2][2] + sm[3][2];
        double aFA = sm[0][3] + sm[1][3] + sm[2][3] + sm[3][3];
        atomicAdd(&acc[0], aT);
        atomicAdd(&acc[1], aF);
        atomicAdd(&acc[2], aC);
        atomicAdd(&acc[3], aFA);
    }
}

__global__ void gsa_final(const double* __restrict__ acc, float* __restrict__ out)
{
    double T   = acc[0];
    double sf  = acc[1];
    double sc  = acc[2];
    double sfa = acc[3];
    double sb  = T - sf;
    double sbb = T - sf - sc + sfa;
    out[0] = (float)(2.0 - sfa / sf - sbb / sb);
}

extern "C" void kernel_launch(void* const* d_in, const int* in_sizes, int n_in,
                              void* d_out, int out_size, void* d_ws, size_t ws_size,
                              hipStream_t stream)
{
    const float* pred  = (const float*)d_in[0];
    const float* token = (const float*)d_in[1];
    float*  out = (float*)d_out;
    double* acc = (double*)d_ws;

    // d_ws is poisoned (0xAA) and never re-poisoned between replays -> zero it
    // every call (async memset is graph-capture-legal).
    hipMemsetAsync(d_ws, 0, 4 * sizeof(double), stream);

    int total4 = in_sizes[1] / 4;  // B*HW*HW/4 = 8,388,608

    // 2048 blocks x 256 threads: ~8 blocks/CU worth of waves, 16 float4/thread
    gsa_reduce<<<2048, 256, 0, stream>>>(pred, token, acc, total4);
    gsa_final<<<1, 1, 0, stream>>>(acc, out);
}

// Round 2
// 117.859 us; speedup vs baseline: 1.0733x; 1.0733x over previous
//
#include <hip/hip_runtime.h>

// GSA loss: pred [B=2,1,64,64] fp32, token [B,4096,4096] fp32 -> scalar fp32.
// loss = 2 - s_fa/s_f - s_bb/s_b with
//   T   = sum t_ij
//   s_f = sum p_i t_ij        (row-weighted)
//   s_c = sum t_ij p_j        (col-weighted; token NOT symmetric)
//   s_fa= sum p_i t_ij p_j
//   s_b = T - s_f
//   s_bb= T - s_f - s_c + s_fa
//
// Structure: one token row (4096 fp32 = 16 KB) per wave, 4 waves/block,
// 2048 blocks x 256 threads = 8192 waves = 8192 rows (B*HW). The row loop is
// a compile-time 16x unrolled float4 loop -> 16 independent global loads in
// flight per wave (latency hiding). pred[b,:] is staged in LDS (16 KB) so the
// p_j operand is a conflict-free ds_read_b128, immune to L1 thrash from the
// token stream.

#define HW   4096
#define HW4  1024   // HW / 4

__global__ __launch_bounds__(256) void gsa_reduce(
    const float* __restrict__ pred,
    const float* __restrict__ token,
    double* __restrict__ acc)   // acc[0..3] = T, s_f, s_c, s_fa
{
    __shared__ float4 pj_lds[HW4];   // 16 KB: pred row for this batch
    __shared__ double sm[4][4];

    const float4* __restrict__ tok4  = (const float4*)token;
    const float4* __restrict__ pred4 = (const float4*)pred;

    const int bid = blockIdx.x;      // 0..2047
    const int b   = bid >> 10;       // rows 4*bid..4*bid+3 are all in batch b

    // stage pred[b, :] into LDS (coalesced: 4 float4 per thread)
    for (int k = threadIdx.x; k < HW4; k += 256)
        pj_lds[k] = pred4[b * HW4 + k];
    __syncthreads();

    const int wave = threadIdx.x >> 6;
    const int lane = threadIdx.x & 63;
    const int row  = bid * 4 + wave;            // global row in [0, B*HW)

    const float pi = pred[row];                 // wave-uniform broadcast load
    const float4* __restrict__ rowp = tok4 + (size_t)row * HW4;

    float s = 0.f, d = 0.f;
#pragma unroll
    for (int u = 0; u < 16; ++u) {
        float4 t  = rowp[u * 64 + lane];        // coalesced 1 KB/wave, independent
        float4 pj = pj_lds[u * 64 + lane];      // conflict-free ds_read_b128
        s += t.x + t.y + t.z + t.w;
        d += t.x * pj.x + t.y * pj.y + t.z * pj.z + t.w * pj.w;
    }

    float tT  = s;
    float tF  = pi * s;
    float tC  = d;
    float tFA = pi * d;

    // wave (64-lane) reduce
    for (int off = 32; off > 0; off >>= 1) {
        tT  += __shfl_down(tT,  off);
        tF  += __shfl_down(tF,  off);
        tC  += __shfl_down(tC,  off);
        tFA += __shfl_down(tFA, off);
    }

    if (lane == 0) {
        sm[wave][0] = (double)tT;
        sm[wave][1] = (double)tF;
        sm[wave][2] = (double)tC;
        sm[wave][3] = (double)tFA;
    }
    __syncthreads();

    if (threadIdx.x == 0) {
        double aT  = sm[0][0] + sm[1][0] + sm[2][0] + sm[3][0];
        double aF  = sm[0][1] + sm[1][1] + sm[2][1] + sm[3][1];
        double aC  = sm[0][2] + sm[1][2] + sm[2][2] + sm[3][2];
        double aFA = sm[0][3] + sm[1][3] + sm[2][3] + sm[3][3];
        atomicAdd(&acc[0], aT);
        atomicAdd(&acc[1], aF);
        atomicAdd(&acc[2], aC);
        atomicAdd(&acc[3], aFA);
    }
}

__global__ void gsa_final(const double* __restrict__ acc, float* __restrict__ out)
{
    double T   = acc[0];
    double sf  = acc[1];
    double sc  = acc[2];
    double sfa = acc[3];
    double sb  = T - sf;
    double sbb = T - sf - sc + sfa;
    out[0] = (float)(2.0 - sfa / sf - sbb / sb);
}

extern "C" void kernel_launch(void* const* d_in, const int* in_sizes, int n_in,
                              void* d_out, int out_size, void* d_ws, size_t ws_size,
                              hipStream_t stream)
{
    const float* pred  = (const float*)d_in[0];
    const float* token = (const float*)d_in[1];
    float*  out = (float*)d_out;
    double* acc = (double*)d_ws;

    // d_ws is poisoned (0xAA) and never re-poisoned between replays -> zero it
    // every call (async memset is graph-capture-legal).
    hipMemsetAsync(d_ws, 0, 4 * sizeof(double), stream);

    // 2048 blocks x 4 waves = 8192 waves = one per token row
    gsa_reduce<<<2048, 256, 0, stream>>>(pred, token, acc);
    gsa_final<<<1, 1, 0, stream>>>(acc, out);
}

// Round 3
// 29.601 us; speedup vs baseline: 4.2737x; 3.9817x over previous
//
#include <hip/hip_runtime.h>

// GSA loss: pred [B=2,1,64,64] fp32, token [B,4096,4096] fp32 -> scalar fp32.
// loss = 2 - s_fa/s_f - s_bb/s_b with
//   T   = sum t_ij
//   s_f = sum p_i t_ij        (row-weighted)
//   s_c = sum t_ij p_j        (col-weighted; token NOT symmetric)
//   s_fa= sum p_i t_ij p_j
//   s_b = T - s_f
//   s_bb= T - s_f - s_c + s_fa
//
// R2 change: NO ATOMICS. R0/R1 spent ~115 us serializing 8192 same-address
// fp64 atomicAdds across 8 XCDs (duration was identical whether data came
// from HBM or L3 -> fixed coherence-serialization bottleneck). Stage 1 writes
// per-block partials to d_ws with plain stores; stage 2 (one block) reduces
// them in fixed order (deterministic) and computes the scalar.

#define HW   4096
#define HW4  1024   // HW / 4
#define NBLK 2048

struct alignas(32) D4 { double t, f, c, fa; };

__global__ __launch_bounds__(256, 4) void gsa_partial(
    const float* __restrict__ pred,
    const float* __restrict__ token,
    D4* __restrict__ part)           // part[NBLK]
{
    __shared__ float4 pj_lds[HW4];   // 16 KB: pred row for this batch
    __shared__ double sm[4][4];

    const float4* __restrict__ tok4  = (const float4*)token;
    const float4* __restrict__ pred4 = (const float4*)pred;

    const int bid = blockIdx.x;      // 0..2047
    const int b   = bid >> 10;       // rows 4*bid..4*bid+3 all in batch b

    for (int k = threadIdx.x; k < HW4; k += 256)
        pj_lds[k] = pred4[b * HW4 + k];
    __syncthreads();

    const int wave = threadIdx.x >> 6;
    const int lane = threadIdx.x & 63;
    const int row  = bid * 4 + wave;            // global row in [0, B*HW)

    const float pi = pred[row];                 // wave-uniform load
    const float4* __restrict__ rowp = tok4 + (size_t)row * HW4;

    // hoist all 16 row loads -> 16 KB/wave in flight (64 VGPRs, cap is 128)
    float4 t[16];
#pragma unroll
    for (int u = 0; u < 16; ++u)
        t[u] = rowp[u * 64 + lane];

    float s = 0.f, d = 0.f;
#pragma unroll
    for (int u = 0; u < 16; ++u) {
        float4 pj = pj_lds[u * 64 + lane];      // conflict-free ds_read_b128
        s += t[u].x + t[u].y + t[u].z + t[u].w;
        d += t[u].x * pj.x + t[u].y * pj.y + t[u].z * pj.z + t[u].w * pj.w;
    }

    float tT  = s;
    float tF  = pi * s;
    float tC  = d;
    float tFA = pi * d;

    for (int off = 32; off > 0; off >>= 1) {
        tT  += __shfl_down(tT,  off);
        tF  += __shfl_down(tF,  off);
        tC  += __shfl_down(tC,  off);
        tFA += __shfl_down(tFA, off);
    }

    if (lane == 0) {
        sm[wave][0] = (double)tT;
        sm[wave][1] = (double)tF;
        sm[wave][2] = (double)tC;
        sm[wave][3] = (double)tFA;
    }
    __syncthreads();

    if (threadIdx.x == 0) {
        D4 p;
        p.t  = sm[0][0] + sm[1][0] + sm[2][0] + sm[3][0];
        p.f  = sm[0][1] + sm[1][1] + sm[2][1] + sm[3][1];
        p.c  = sm[0][2] + sm[1][2] + sm[2][2] + sm[3][2];
        p.fa = sm[0][3] + sm[1][3] + sm[2][3] + sm[3][3];
        part[bid] = p;               // plain store — no atomics
    }
}

__global__ __launch_bounds__(256) void gsa_final(
    const D4* __restrict__ part, float* __restrict__ out)
{
    double aT = 0.0, aF = 0.0, aC = 0.0, aFA = 0.0;
    for (int k = threadIdx.x; k < NBLK; k += 256) {
        D4 p = part[k];
        aT += p.t; aF += p.f; aC += p.c; aFA += p.fa;
    }

    for (int off = 32; off > 0; off >>= 1) {
        aT  += __shfl_down(aT,  off);
        aF  += __shfl_down(aF,  off);
        aC  += __shfl_down(aC,  off);
        aFA += __shfl_down(aFA, off);
    }

    __shared__ double sm[4][4];
    const int wave = threadIdx.x >> 6;
    const int lane = threadIdx.x & 63;
    if (lane == 0) {
        sm[wave][0] = aT; sm[wave][1] = aF;
        sm[wave][2] = aC; sm[wave][3] = aFA;
    }
    __syncthreads();

    if (threadIdx.x == 0) {
        double T   = sm[0][0] + sm[1][0] + sm[2][0] + sm[3][0];
        double sf  = sm[0][1] + sm[1][1] + sm[2][1] + sm[3][1];
        double sc  = sm[0][2] + sm[1][2] + sm[2][2] + sm[3][2];
        double sfa = sm[0][3] + sm[1][3] + sm[2][3] + sm[3][3];
        double sb  = T - sf;
        double sbb = T - sf - sc + sfa;
        out[0] = (float)(2.0 - sfa / sf - sbb / sb);
    }
}

extern "C" void kernel_launch(void* const* d_in, const int* in_sizes, int n_in,
                              void* d_out, int out_size, void* d_ws, size_t ws_size,
                              hipStream_t stream)
{
    const float* pred  = (const float*)d_in[0];
    const float* token = (const float*)d_in[1];
    float* out = (float*)d_out;
    D4*    part = (D4*)d_ws;         // 2048 * 32 B = 64 KB scratch

    // stage 1: one token row per wave, per-block partials (no memset needed —
    // every part[] slot is overwritten every call)
    gsa_partial<<<NBLK, 256, 0, stream>>>(pred, token, part);
    // stage 2: deterministic fixed-order reduction + scalar epilogue
    gsa_final<<<1, 256, 0, stream>>>(part, out);
}